// Round 3
// baseline (358.565 us; speedup 1.0000x reference)
//
#include <hip/hip_runtime.h>

// RowAttentionWithPairBias  (B=1, M=128, N=256, C_IN=256, C_PAIR=128, H=8, C=32)
// Harness contract (established r0-r2): inputs fp32, OUTPUT fp32 (bf16-level
// tolerance). Internal compute: bf16 MFMA, fp32 accumulation.
// Verified fragment layouts (learn_hip m89/m91/m92/m120), v_mfma_f32_16x16x32_bf16:
//   A: lane holds A[m=lane&15][k=(lane>>4)*8 + j], j=0..7
//   B: lane holds B[k=(lane>>4)*8 + j][n=lane&15]
//   C/D: col = lane&15, row = (lane>>4)*4 + reg

typedef unsigned short u16;
typedef unsigned int   u32;
typedef __attribute__((ext_vector_type(8))) __bf16 bf16x8;
typedef __attribute__((ext_vector_type(4))) float  f32x4;

#define DEV __device__ __forceinline__

DEV float bf2f(u16 s) {
    u32 u = ((u32)s) << 16;
    float f;
    __builtin_memcpy(&f, &u, 4);
    return f;
}
DEV u16 f2bf(float f) {
    u32 u;
    __builtin_memcpy(&u, &f, 4);
    u = (u + 0x7fffu + ((u >> 16) & 1u)) >> 16;   // round-to-nearest-even
    return (u16)u;
}

// ---------------------------------------------------------------- transpose W (fp32 -> bf16)
// WT[1024][256]: rows 0-255 Wq^T, 256-511 Wk^T, 512-767 Wv^T, 768-1023 Wgate^T
// WfT[256][256] = Wfinal^T
__global__ void k_transpose(const float* __restrict__ Wq, const float* __restrict__ Wk,
                            const float* __restrict__ Wv, const float* __restrict__ Wg,
                            const float* __restrict__ Wf,
                            u16* __restrict__ WT, u16* __restrict__ WfT) {
    int idx = blockIdx.x * 256 + threadIdx.x;
    if (idx < 1024 * 256) {
        int gcol = idx >> 8, p = idx & 255;
        int sel = gcol >> 8, c = gcol & 255;
        const float* W = sel == 0 ? Wq : sel == 1 ? Wk : sel == 2 ? Wv : Wg;
        WT[idx] = f2bf(W[p * 256 + c]);
    } else {
        int j = idx - 1024 * 256;            // [0, 65536)
        int d = j >> 8, hc = j & 255;
        WfT[j] = f2bf(Wf[hc * 256 + d]);
    }
}

// ---------------------------------------------------------------- LayerNorm 1
// x1d [32768][256] fp32 -> x1 [32768][256] bf16.  One wave per row.
__global__ __launch_bounds__(256) void k_ln1(const float* __restrict__ x,
                                             const float* __restrict__ gg,
                                             const float* __restrict__ bb,
                                             u16* __restrict__ y) {
    int lane = threadIdx.x & 63, wave = threadIdx.x >> 6;
    int row = blockIdx.x * 4 + wave;
    float4 xv = *(const float4*)(x + row * 256 + lane * 4);
    float v0 = xv.x, v1 = xv.y, v2 = xv.z, v3 = xv.w;
    float s  = v0 + v1 + v2 + v3;
    float s2 = v0*v0 + v1*v1 + v2*v2 + v3*v3;
    #pragma unroll
    for (int msk = 32; msk; msk >>= 1) {
        s  += __shfl_xor(s,  msk, 64);
        s2 += __shfl_xor(s2, msk, 64);
    }
    float mu  = s * (1.0f / 256.0f);
    float var = s2 * (1.0f / 256.0f) - mu * mu;
    float rs  = rsqrtf(var + 1e-5f);
    float4 gv = *(const float4*)(gg + lane * 4);
    float4 bv = *(const float4*)(bb + lane * 4);
    ushort4 o;
    o.x = f2bf((v0 - mu) * rs * gv.x + bv.x);
    o.y = f2bf((v1 - mu) * rs * gv.y + bv.y);
    o.z = f2bf((v2 - mu) * rs * gv.z + bv.z);
    o.w = f2bf((v3 - mu) * rs * gv.w + bv.w);
    *(ushort4*)(y + row * 256 + lane * 4) = o;
}

// ---------------------------------------------------------------- LN2 + pair bias
// x2d [65536][128] fp32 -> bias[h][i][j] fp32  (bias[h*65536 + i*256 + j])
__global__ __launch_bounds__(256) void k_ln2bias(const float* __restrict__ x2,
                                                 const float* __restrict__ gg,
                                                 const float* __restrict__ bb,
                                                 const float* __restrict__ W2d,
                                                 float* __restrict__ bias) {
    int lane = threadIdx.x & 63, wave = threadIdx.x >> 6;
    int row = blockIdx.x * 4 + wave;                 // row = i*256 + j
    float2 xv = *(const float2*)(x2 + row * 128 + lane * 2);
    float v0 = xv.x, v1 = xv.y;
    float s = v0 + v1, s2 = v0*v0 + v1*v1;
    #pragma unroll
    for (int msk = 32; msk; msk >>= 1) {
        s  += __shfl_xor(s,  msk, 64);
        s2 += __shfl_xor(s2, msk, 64);
    }
    float mu  = s * (1.0f / 128.0f);
    float var = s2 * (1.0f / 128.0f) - mu * mu;
    float rs  = rsqrtf(var + 1e-5f);
    float2 gv = *(const float2*)(gg + lane * 2);
    float2 bv = *(const float2*)(bb + lane * 2);
    float xn0 = (v0 - mu) * rs * gv.x + bv.x;
    float xn1 = (v1 - mu) * rs * gv.y + bv.y;
    int p0 = lane * 2;
    float4 w0a = *(const float4*)(W2d + p0 * 8);
    float4 w0b = *(const float4*)(W2d + p0 * 8 + 4);
    float4 w1a = *(const float4*)(W2d + (p0 + 1) * 8);
    float4 w1b = *(const float4*)(W2d + (p0 + 1) * 8 + 4);
    float p[8];
    p[0] = xn0 * w0a.x + xn1 * w1a.x;
    p[1] = xn0 * w0a.y + xn1 * w1a.y;
    p[2] = xn0 * w0a.z + xn1 * w1a.z;
    p[3] = xn0 * w0a.w + xn1 * w1a.w;
    p[4] = xn0 * w0b.x + xn1 * w1b.x;
    p[5] = xn0 * w0b.y + xn1 * w1b.y;
    p[6] = xn0 * w0b.z + xn1 * w1b.z;
    p[7] = xn0 * w0b.w + xn1 * w1b.w;
    #pragma unroll
    for (int hh = 0; hh < 8; hh++)
        #pragma unroll
        for (int msk = 32; msk; msk >>= 1)
            p[hh] += __shfl_xor(p[hh], msk, 64);
    if (lane == 0) {
        #pragma unroll
        for (int hh = 0; hh < 8; hh++)
            bias[hh * 65536 + row] = p[hh];
    }
}

// ---------------------------------------------------------------- 64x64 MFMA wave tile
// X row-major [rows][K] bf16, WTb row-major [cols][K] (i.e. W^T) bf16.
DEV void mfma_tile64(const u16* __restrict__ X, const u16* __restrict__ WTb,
                     int rowbase, int colbase, int K, f32x4 acc[4][4], int lane) {
    int lrow = lane & 15, lk = (lane >> 4) * 8;
    for (int kk = 0; kk < K; kk += 32) {
        bf16x8 af[4], bf[4];
        #pragma unroll
        for (int t = 0; t < 4; t++)
            af[t] = *(const bf16x8*)(X + (rowbase + t * 16 + lrow) * K + kk + lk);
        #pragma unroll
        for (int t = 0; t < 4; t++)
            bf[t] = *(const bf16x8*)(WTb + (colbase + t * 16 + lrow) * K + kk + lk);
        #pragma unroll
        for (int i = 0; i < 4; i++)
            #pragma unroll
            for (int j = 0; j < 4; j++)
                acc[i][j] = __builtin_amdgcn_mfma_f32_16x16x32_bf16(af[i], bf[j], acc[i][j], 0, 0, 0);
    }
}

// ---------------------------------------------------------------- QKVG projection
// X=x1 [32768][256] @ WT -> cols 0-255 q (scaled), 256-511 k, 512-767 v (stored
// transposed vt[m][o][i]), 768-1023 gate (sigmoid applied).
// grid (256, 8), block 256.  Block tile 128x128, wave tile 64x64.
__global__ __launch_bounds__(256) void k_qkvg(const u16* __restrict__ X, const u16* __restrict__ WT,
                                              u16* __restrict__ q, u16* __restrict__ kb,
                                              u16* __restrict__ vt, u16* __restrict__ gt,
                                              const float* __restrict__ bgate) {
    int lane = threadIdx.x & 63, wave = threadIdx.x >> 6;
    int rowbase = blockIdx.x * 128 + (wave >> 1) * 64;
    int colbase = blockIdx.y * 128 + (wave & 1) * 64;
    f32x4 acc[4][4];
    #pragma unroll
    for (int i = 0; i < 4; i++)
        #pragma unroll
        for (int j = 0; j < 4; j++)
            acc[i][j] = (f32x4){0.f, 0.f, 0.f, 0.f};
    mfma_tile64(X, WT, rowbase, colbase, 256, acc, lane);
    int lrow = lane & 15, quad = lane >> 4;
    int which = blockIdx.y >> 1;          // uniform per block: 0=q 1=k 2=v 3=gate
    #pragma unroll
    for (int it = 0; it < 4; it++)
        #pragma unroll
        for (int jt = 0; jt < 4; jt++)
            #pragma unroll
            for (int r = 0; r < 4; r++) {
                int grow = rowbase + it * 16 + quad * 4 + r;
                int gcol = colbase + jt * 16 + lrow;
                int o = gcol & 255;
                float v = acc[it][jt][r];
                if (which == 0) {
                    q[grow * 256 + o] = f2bf(v * 0.17677669529663687f);   // 1/sqrt(32)
                } else if (which == 1) {
                    kb[grow * 256 + o] = f2bf(v);
                } else if (which == 2) {
                    int mm = grow >> 8, ii = grow & 255;
                    vt[(mm * 256 + o) * 256 + ii] = f2bf(v);
                } else {
                    float z = v + bgate[o];
                    gt[grow * 256 + o] = f2bf(1.0f / (1.0f + __expf(-z)));
                }
            }
}

// ---------------------------------------------------------------- attention
// grid (m=128, h=8, iblk=4), block 256 (4 waves, 16 q-rows each).
__global__ __launch_bounds__(256) void k_attn(const u16* __restrict__ q, const u16* __restrict__ kb,
                                              const u16* __restrict__ vt, const u16* __restrict__ gt,
                                              const float* __restrict__ bias,
                                              u16* __restrict__ tmp) {
    __shared__ u16 P[4][16][264];          // +8 pad
    int lane = threadIdx.x & 63, wave = threadIdx.x >> 6;
    int lrow = lane & 15, quad = lane >> 4, lk = quad * 8;
    int m = blockIdx.x, h = blockIdx.y, iblk = blockIdx.z;
    int i0 = iblk * 64 + wave * 16;

    // ---- QK^T : one MFMA per 16-col j tile, K=32 in one shot
    bf16x8 aq = *(const bf16x8*)(q + (m * 256 + i0 + lrow) * 256 + h * 32 + lk);
    f32x4 acc[16];
    #pragma unroll
    for (int jt = 0; jt < 16; jt++) {
        bf16x8 bk = *(const bf16x8*)(kb + (m * 256 + jt * 16 + lrow) * 256 + h * 32 + lk);
        f32x4 z = {0.f, 0.f, 0.f, 0.f};
        acc[jt] = __builtin_amdgcn_mfma_f32_16x16x32_bf16(aq, bk, z, 0, 0, 0);
    }

    // ---- bias add + softmax over j, in registers (rows live in 16-lane quads)
    float rmax[4] = {-1e30f, -1e30f, -1e30f, -1e30f};
    #pragma unroll
    for (int jt = 0; jt < 16; jt++)
        #pragma unroll
        for (int r = 0; r < 4; r++) {
            int i = i0 + quad * 4 + r;
            int j = jt * 16 + lrow;
            float a = acc[jt][r] + bias[h * 65536 + i * 256 + j];
            acc[jt][r] = a;
            rmax[r] = fmaxf(rmax[r], a);
        }
    #pragma unroll
    for (int r = 0; r < 4; r++)
        #pragma unroll
        for (int msk = 8; msk; msk >>= 1)
            rmax[r] = fmaxf(rmax[r], __shfl_xor(rmax[r], msk, 64));
    float rsum[4] = {0.f, 0.f, 0.f, 0.f};
    #pragma unroll
    for (int jt = 0; jt < 16; jt++)
        #pragma unroll
        for (int r = 0; r < 4; r++) {
            float e = __expf(acc[jt][r] - rmax[r]);
            acc[jt][r] = e;
            rsum[r] += e;
        }
    #pragma unroll
    for (int r = 0; r < 4; r++) {
        #pragma unroll
        for (int msk = 8; msk; msk >>= 1)
            rsum[r] += __shfl_xor(rsum[r], msk, 64);
        rsum[r] = 1.0f / fmaxf(rsum[r], 1e-30f);
    }

    // ---- P to LDS (C-layout -> A-layout transform)
    #pragma unroll
    for (int jt = 0; jt < 16; jt++)
        #pragma unroll
        for (int r = 0; r < 4; r++)
            P[wave][quad * 4 + r][jt * 16 + lrow] = f2bf(acc[jt][r] * rsum[r]);
    __syncthreads();

    // ---- PV : out[16 i][32 c], K=256 over j
    f32x4 oacc[2] = {{0.f,0.f,0.f,0.f}, {0.f,0.f,0.f,0.f}};
    const u16* Pw = &P[wave][0][0];
    for (int kk2 = 0; kk2 < 256; kk2 += 32) {
        bf16x8 ap = *(const bf16x8*)(Pw + lrow * 264 + kk2 + lk);
        #pragma unroll
        for (int ct = 0; ct < 2; ct++) {
            bf16x8 bv = *(const bf16x8*)(vt + (m * 256 + h * 32 + ct * 16 + lrow) * 256 + kk2 + lk);
            oacc[ct] = __builtin_amdgcn_mfma_f32_16x16x32_bf16(ap, bv, oacc[ct], 0, 0, 0);
        }
    }

    // ---- gate multiply + store gated output [m,i,h,c]
    #pragma unroll
    for (int ct = 0; ct < 2; ct++)
        #pragma unroll
        for (int r = 0; r < 4; r++) {
            int i = i0 + quad * 4 + r;
            int o = h * 32 + ct * 16 + lrow;
            float gv = bf2f(gt[(m * 256 + i) * 256 + o]);
            tmp[(m * 256 + i) * 256 + o] = f2bf(oacc[ct][r] * gv);
        }
}

// ---------------------------------------------------------------- final projection
// tmp [32768][256] @ WfT + bfinal -> out FP32.  grid (256, 2).
__global__ __launch_bounds__(256) void k_final(const u16* __restrict__ T, const u16* __restrict__ WfT,
                                               const float* __restrict__ bfinal, float* __restrict__ out) {
    int lane = threadIdx.x & 63, wave = threadIdx.x >> 6;
    int rowbase = blockIdx.x * 128 + (wave >> 1) * 64;
    int colbase = blockIdx.y * 128 + (wave & 1) * 64;
    f32x4 acc[4][4];
    #pragma unroll
    for (int i = 0; i < 4; i++)
        #pragma unroll
        for (int j = 0; j < 4; j++)
            acc[i][j] = (f32x4){0.f, 0.f, 0.f, 0.f};
    mfma_tile64(T, WfT, rowbase, colbase, 256, acc, lane);
    int lrow = lane & 15, quad = lane >> 4;
    #pragma unroll
    for (int it = 0; it < 4; it++)
        #pragma unroll
        for (int jt = 0; jt < 4; jt++)
            #pragma unroll
            for (int r = 0; r < 4; r++) {
                int grow = rowbase + it * 16 + quad * 4 + r;
                int gcol = colbase + jt * 16 + lrow;
                out[grow * 256 + gcol] = acc[it][jt][r] + bfinal[gcol];
            }
}

// ---------------------------------------------------------------- launch
extern "C" void kernel_launch(void* const* d_in, const int* in_sizes, int n_in,
                              void* d_out, int out_size, void* d_ws, size_t ws_size,
                              hipStream_t stream) {
    const float* x1d   = (const float*)d_in[0];
    const float* x2d   = (const float*)d_in[1];
    const float* ln1_g = (const float*)d_in[2];
    const float* ln1_b = (const float*)d_in[3];
    const float* ln2_g = (const float*)d_in[4];
    const float* ln2_b = (const float*)d_in[5];
    const float* Wq    = (const float*)d_in[6];
    const float* Wk    = (const float*)d_in[7];
    const float* Wv    = (const float*)d_in[8];
    const float* W2d   = (const float*)d_in[9];
    const float* Wg    = (const float*)d_in[10];
    const float* bg    = (const float*)d_in[11];
    const float* Wf    = (const float*)d_in[12];
    const float* bfin  = (const float*)d_in[13];
    float* out = (float*)d_out;

    char* ws = (char*)d_ws;
    u16*   x1   = (u16*)(ws);                    // 16,777,216 B  (reused as tmp)
    u16*   WT   = (u16*)(ws + 16777216);         //    524,288 B
    u16*   WfT  = (u16*)(ws + 17301504);         //    131,072 B
    float* bias = (float*)(ws + 17432576);       //  2,097,152 B
    u16*   qb   = (u16*)(ws + 19529728);         // 16,777,216 B
    u16*   kb   = (u16*)(ws + 36306944);         // 16,777,216 B
    u16*   vtb  = (u16*)(ws + 53084160);         // 16,777,216 B
    u16*   gb   = (u16*)(ws + 69861376);         // 16,777,216 B  (end: 86,638,592)
    u16*   tmp  = x1;                            // x1 dead after k_qkvg

    k_transpose<<<1280, 256, 0, stream>>>(Wq, Wk, Wv, Wg, Wf, WT, WfT);
    k_ln1<<<8192, 256, 0, stream>>>(x1d, ln1_g, ln1_b, x1);
    k_ln2bias<<<16384, 256, 0, stream>>>(x2d, ln2_g, ln2_b, W2d, bias);
    k_qkvg<<<dim3(256, 8), 256, 0, stream>>>(x1, WT, qb, kb, vtb, gb, bg);
    k_attn<<<dim3(128, 8, 4), 256, 0, stream>>>(qb, kb, vtb, gb, bias, tmp);
    k_final<<<dim3(256, 2), 256, 0, stream>>>(tmp, WfT, bfin, out);
}

// Round 4
// 312.849 us; speedup vs baseline: 1.1461x; 1.1461x over previous
//
#include <hip/hip_runtime.h>

// RowAttentionWithPairBias  (B=1, M=128, N=256, C_IN=256, C_PAIR=128, H=8, C=32)
// Harness contract (established r0-r3): inputs fp32, OUTPUT fp32 (bf16-level
// tolerance). Internal compute: bf16 MFMA, fp32 accumulation.
// R4: k_qkvg/k_final use m97-style staged GEMM core: global_load_lds width=16,
// XOR-swizzled LDS ([row][chunk^(row&7)]) -> ds_read_b128 conflict-free (2-way).
// Verified fragment layouts (learn_hip m89/m91/m92/m120), v_mfma_f32_16x16x32_bf16:
//   A: lane holds A[m=lane&15][k=(lane>>4)*8 + j], j=0..7
//   B: lane holds B[k=(lane>>4)*8 + j][n=lane&15]
//   C/D: col = lane&15, row = (lane>>4)*4 + reg

typedef unsigned short u16;
typedef unsigned int   u32;
typedef __attribute__((ext_vector_type(8))) __bf16 bf16x8;
typedef __attribute__((ext_vector_type(4))) float  f32x4;

#define DEV __device__ __forceinline__

DEV float bf2f(u16 s) {
    u32 u = ((u32)s) << 16;
    float f;
    __builtin_memcpy(&f, &u, 4);
    return f;
}
DEV u16 f2bf(float f) {
    u32 u;
    __builtin_memcpy(&u, &f, 4);
    u = (u + 0x7fffu + ((u >> 16) & 1u)) >> 16;   // round-to-nearest-even
    return (u16)u;
}

// async global->LDS, 16 B per lane; LDS dest wave-uniform base + lane*16
#define GLD_LDS16(gp, lp)                                                           \
    __builtin_amdgcn_global_load_lds(                                               \
        (const __attribute__((address_space(1))) u32*)(const void*)(gp),            \
        (__attribute__((address_space(3))) u32*)(void*)(lp), 16, 0, 0)

// ---------------------------------------------------------------- transpose W (fp32 -> bf16)
// WT[1024][256]: rows 0-255 Wq^T, 256-511 Wk^T, 512-767 Wv^T, 768-1023 Wgate^T
// WfT[256][256] = Wfinal^T
__global__ void k_transpose(const float* __restrict__ Wq, const float* __restrict__ Wk,
                            const float* __restrict__ Wv, const float* __restrict__ Wg,
                            const float* __restrict__ Wf,
                            u16* __restrict__ WT, u16* __restrict__ WfT) {
    int idx = blockIdx.x * 256 + threadIdx.x;
    if (idx < 1024 * 256) {
        int gcol = idx >> 8, p = idx & 255;
        int sel = gcol >> 8, c = gcol & 255;
        const float* W = sel == 0 ? Wq : sel == 1 ? Wk : sel == 2 ? Wv : Wg;
        WT[idx] = f2bf(W[p * 256 + c]);
    } else {
        int j = idx - 1024 * 256;            // [0, 65536)
        int d = j >> 8, hc = j & 255;
        WfT[j] = f2bf(Wf[hc * 256 + d]);
    }
}

// ---------------------------------------------------------------- LayerNorm 1
// x1d [32768][256] fp32 -> x1 [32768][256] bf16.  One wave per row.
__global__ __launch_bounds__(256) void k_ln1(const float* __restrict__ x,
                                             const float* __restrict__ gg,
                                             const float* __restrict__ bb,
                                             u16* __restrict__ y) {
    int lane = threadIdx.x & 63, wave = threadIdx.x >> 6;
    int row = blockIdx.x * 4 + wave;
    float4 xv = *(const float4*)(x + row * 256 + lane * 4);
    float v0 = xv.x, v1 = xv.y, v2 = xv.z, v3 = xv.w;
    float s  = v0 + v1 + v2 + v3;
    float s2 = v0*v0 + v1*v1 + v2*v2 + v3*v3;
    #pragma unroll
    for (int msk = 32; msk; msk >>= 1) {
        s  += __shfl_xor(s,  msk, 64);
        s2 += __shfl_xor(s2, msk, 64);
    }
    float mu  = s * (1.0f / 256.0f);
    float var = s2 * (1.0f / 256.0f) - mu * mu;
    float rs  = rsqrtf(var + 1e-5f);
    float4 gv = *(const float4*)(gg + lane * 4);
    float4 bv = *(const float4*)(bb + lane * 4);
    ushort4 o;
    o.x = f2bf((v0 - mu) * rs * gv.x + bv.x);
    o.y = f2bf((v1 - mu) * rs * gv.y + bv.y);
    o.z = f2bf((v2 - mu) * rs * gv.z + bv.z);
    o.w = f2bf((v3 - mu) * rs * gv.w + bv.w);
    *(ushort4*)(y + row * 256 + lane * 4) = o;
}

// ---------------------------------------------------------------- LN2 + pair bias
// x2d [65536][128] fp32 -> bias[h][i][j] fp32  (bias[h*65536 + i*256 + j])
__global__ __launch_bounds__(256) void k_ln2bias(const float* __restrict__ x2,
                                                 const float* __restrict__ gg,
                                                 const float* __restrict__ bb,
                                                 const float* __restrict__ W2d,
                                                 float* __restrict__ bias) {
    int lane = threadIdx.x & 63, wave = threadIdx.x >> 6;
    int row = blockIdx.x * 4 + wave;                 // row = i*256 + j
    float2 xv = *(const float2*)(x2 + row * 128 + lane * 2);
    float v0 = xv.x, v1 = xv.y;
    float s = v0 + v1, s2 = v0*v0 + v1*v1;
    #pragma unroll
    for (int msk = 32; msk; msk >>= 1) {
        s  += __shfl_xor(s,  msk, 64);
        s2 += __shfl_xor(s2, msk, 64);
    }
    float mu  = s * (1.0f / 128.0f);
    float var = s2 * (1.0f / 128.0f) - mu * mu;
    float rs  = rsqrtf(var + 1e-5f);
    float2 gv = *(const float2*)(gg + lane * 2);
    float2 bv = *(const float2*)(bb + lane * 2);
    float xn0 = (v0 - mu) * rs * gv.x + bv.x;
    float xn1 = (v1 - mu) * rs * gv.y + bv.y;
    int p0 = lane * 2;
    float4 w0a = *(const float4*)(W2d + p0 * 8);
    float4 w0b = *(const float4*)(W2d + p0 * 8 + 4);
    float4 w1a = *(const float4*)(W2d + (p0 + 1) * 8);
    float4 w1b = *(const float4*)(W2d + (p0 + 1) * 8 + 4);
    float p[8];
    p[0] = xn0 * w0a.x + xn1 * w1a.x;
    p[1] = xn0 * w0a.y + xn1 * w1a.y;
    p[2] = xn0 * w0a.z + xn1 * w1a.z;
    p[3] = xn0 * w0a.w + xn1 * w1a.w;
    p[4] = xn0 * w0b.x + xn1 * w1b.x;
    p[5] = xn0 * w0b.y + xn1 * w1b.y;
    p[6] = xn0 * w0b.z + xn1 * w1b.z;
    p[7] = xn0 * w0b.w + xn1 * w1b.w;
    #pragma unroll
    for (int hh = 0; hh < 8; hh++)
        #pragma unroll
        for (int msk = 32; msk; msk >>= 1)
            p[hh] += __shfl_xor(p[hh], msk, 64);
    if (lane == 0) {
        #pragma unroll
        for (int hh = 0; hh < 8; hh++)
            bias[hh * 65536 + row] = p[hh];
    }
}

// ---------------------------------------------------------------- staged 128x128 GEMM core
// C[128x128 tile] = X[rowbase..+127][0..K) * WTb[colbase..+127][0..K)^T
// As/Bs: [128][64] u16, chunk-swizzled: phys chunk p of row r holds logical
// chunk p ^ (r&7)  (chunk = 8 u16 = 16 B).  BK=64, 2-barrier K-loop.
DEV void gemm128_core(const u16* __restrict__ X, const u16* __restrict__ WTb,
                      int rowbase, int colbase, int K,
                      u16* As, u16* Bs, f32x4 acc[4][4], int lane, int wave) {
    int l8 = lane & 7, r8 = lane >> 3;       // chunk-in-row, row-in-segment (8 rows/instr)
    int gchunk = l8 ^ (r8 & 7);              // xor swizzle: phys chunk l8 <- logical chunk l8^r8
    int lrow = lane & 15, quad = lane >> 4;
    int wr = (wave >> 1) * 64, wc = (wave & 1) * 64;

    for (int kk = 0; kk < K; kk += 64) {
        #pragma unroll
        for (int i = 0; i < 4; i++) {
            int s = wave * 4 + i;                            // segment 0..15 (8 rows each)
            const u16* g = X + (rowbase + s * 8 + r8) * K + kk + gchunk * 8;
            GLD_LDS16(g, As + s * 512);
        }
        #pragma unroll
        for (int i = 0; i < 4; i++) {
            int s = wave * 4 + i;
            const u16* g = WTb + (colbase + s * 8 + r8) * K + kk + gchunk * 8;
            GLD_LDS16(g, Bs + s * 512);
        }
        __syncthreads();                                     // waits vmcnt(0) for the DMA
        #pragma unroll
        for (int k2 = 0; k2 < 64; k2 += 32) {
            int cidx = (k2 >> 3) + quad;                     // logical chunk 0..7
            bf16x8 af[4], bf[4];
            #pragma unroll
            for (int t = 0; t < 4; t++) {
                int R = wr + t * 16 + lrow;
                af[t] = *(const bf16x8*)(As + R * 64 + ((cidx ^ (R & 7)) << 3));
            }
            #pragma unroll
            for (int t = 0; t < 4; t++) {
                int R = wc + t * 16 + lrow;
                bf[t] = *(const bf16x8*)(Bs + R * 64 + ((cidx ^ (R & 7)) << 3));
            }
            #pragma unroll
            for (int i = 0; i < 4; i++)
                #pragma unroll
                for (int j = 0; j < 4; j++)
                    acc[i][j] = __builtin_amdgcn_mfma_f32_16x16x32_bf16(af[i], bf[j], acc[i][j], 0, 0, 0);
        }
        __syncthreads();
    }
}

// ---------------------------------------------------------------- QKVG projection
// X=x1 [32768][256] @ WT -> cols 0-255 q (scaled), 256-511 k, 512-767 v (stored
// transposed vt[m][o][i]), 768-1023 gate (sigmoid applied).
// grid (256, 8), block 256.  Block tile 128x128, wave tile 64x64.
__global__ __launch_bounds__(256) void k_qkvg(const u16* __restrict__ X, const u16* __restrict__ WT,
                                              u16* __restrict__ q, u16* __restrict__ kb,
                                              u16* __restrict__ vt, u16* __restrict__ gt,
                                              const float* __restrict__ bgate) {
    __shared__ u16 As[128 * 64];
    __shared__ u16 Bs[128 * 64];
    int lane = threadIdx.x & 63, wave = threadIdx.x >> 6;
    int rowbase = blockIdx.x * 128;
    int colbase = blockIdx.y * 128;
    f32x4 acc[4][4];
    #pragma unroll
    for (int i = 0; i < 4; i++)
        #pragma unroll
        for (int j = 0; j < 4; j++)
            acc[i][j] = (f32x4){0.f, 0.f, 0.f, 0.f};
    gemm128_core(X, WT, rowbase, colbase, 256, As, Bs, acc, lane, wave);
    int lrow = lane & 15, quad = lane >> 4;
    int wrb = rowbase + (wave >> 1) * 64, wcb = colbase + (wave & 1) * 64;
    int which = blockIdx.y >> 1;          // uniform per block: 0=q 1=k 2=v 3=gate
    #pragma unroll
    for (int it = 0; it < 4; it++)
        #pragma unroll
        for (int jt = 0; jt < 4; jt++)
            #pragma unroll
            for (int r = 0; r < 4; r++) {
                int grow = wrb + it * 16 + quad * 4 + r;
                int gcol = wcb + jt * 16 + lrow;
                int o = gcol & 255;
                float v = acc[it][jt][r];
                if (which == 0) {
                    q[grow * 256 + o] = f2bf(v * 0.17677669529663687f);   // 1/sqrt(32)
                } else if (which == 1) {
                    kb[grow * 256 + o] = f2bf(v);
                } else if (which == 2) {
                    int mm = grow >> 8, ii = grow & 255;
                    vt[(mm * 256 + o) * 256 + ii] = f2bf(v);
                } else {
                    float z = v + bgate[o];
                    gt[grow * 256 + o] = f2bf(1.0f / (1.0f + __expf(-z)));
                }
            }
}

// ---------------------------------------------------------------- attention
// grid (m=128, h=8, iblk=4), block 256 (4 waves, 16 q-rows each).
__global__ __launch_bounds__(256) void k_attn(const u16* __restrict__ q, const u16* __restrict__ kb,
                                              const u16* __restrict__ vt, const u16* __restrict__ gt,
                                              const float* __restrict__ bias,
                                              u16* __restrict__ tmp) {
    __shared__ u16 P[4][16][264];          // +8 pad
    int lane = threadIdx.x & 63, wave = threadIdx.x >> 6;
    int lrow = lane & 15, quad = lane >> 4, lk = quad * 8;
    int m = blockIdx.x, h = blockIdx.y, iblk = blockIdx.z;
    int i0 = iblk * 64 + wave * 16;

    // ---- QK^T : one MFMA per 16-col j tile, K=32 in one shot
    bf16x8 aq = *(const bf16x8*)(q + (m * 256 + i0 + lrow) * 256 + h * 32 + lk);
    f32x4 acc[16];
    #pragma unroll
    for (int jt = 0; jt < 16; jt++) {
        bf16x8 bk = *(const bf16x8*)(kb + (m * 256 + jt * 16 + lrow) * 256 + h * 32 + lk);
        f32x4 z = {0.f, 0.f, 0.f, 0.f};
        acc[jt] = __builtin_amdgcn_mfma_f32_16x16x32_bf16(aq, bk, z, 0, 0, 0);
    }

    // ---- bias add + softmax over j, in registers (rows live in 16-lane quads)
    float rmax[4] = {-1e30f, -1e30f, -1e30f, -1e30f};
    #pragma unroll
    for (int jt = 0; jt < 16; jt++)
        #pragma unroll
        for (int r = 0; r < 4; r++) {
            int i = i0 + quad * 4 + r;
            int j = jt * 16 + lrow;
            float a = acc[jt][r] + bias[h * 65536 + i * 256 + j];
            acc[jt][r] = a;
            rmax[r] = fmaxf(rmax[r], a);
        }
    #pragma unroll
    for (int r = 0; r < 4; r++)
        #pragma unroll
        for (int msk = 8; msk; msk >>= 1)
            rmax[r] = fmaxf(rmax[r], __shfl_xor(rmax[r], msk, 64));
    float rsum[4] = {0.f, 0.f, 0.f, 0.f};
    #pragma unroll
    for (int jt = 0; jt < 16; jt++)
        #pragma unroll
        for (int r = 0; r < 4; r++) {
            float e = __expf(acc[jt][r] - rmax[r]);
            acc[jt][r] = e;
            rsum[r] += e;
        }
    #pragma unroll
    for (int r = 0; r < 4; r++) {
        #pragma unroll
        for (int msk = 8; msk; msk >>= 1)
            rsum[r] += __shfl_xor(rsum[r], msk, 64);
        rsum[r] = 1.0f / fmaxf(rsum[r], 1e-30f);
    }

    // ---- P to LDS (C-layout -> A-layout transform)
    #pragma unroll
    for (int jt = 0; jt < 16; jt++)
        #pragma unroll
        for (int r = 0; r < 4; r++)
            P[wave][quad * 4 + r][jt * 16 + lrow] = f2bf(acc[jt][r] * rsum[r]);
    __syncthreads();

    // ---- PV : out[16 i][32 c], K=256 over j
    f32x4 oacc[2] = {{0.f,0.f,0.f,0.f}, {0.f,0.f,0.f,0.f}};
    const u16* Pw = &P[wave][0][0];
    for (int kk2 = 0; kk2 < 256; kk2 += 32) {
        bf16x8 ap = *(const bf16x8*)(Pw + lrow * 264 + kk2 + lk);
        #pragma unroll
        for (int ct = 0; ct < 2; ct++) {
            bf16x8 bv = *(const bf16x8*)(vt + (m * 256 + h * 32 + ct * 16 + lrow) * 256 + kk2 + lk);
            oacc[ct] = __builtin_amdgcn_mfma_f32_16x16x32_bf16(ap, bv, oacc[ct], 0, 0, 0);
        }
    }

    // ---- gate multiply + store gated output [m,i,h,c]
    #pragma unroll
    for (int ct = 0; ct < 2; ct++)
        #pragma unroll
        for (int r = 0; r < 4; r++) {
            int i = i0 + quad * 4 + r;
            int o = h * 32 + ct * 16 + lrow;
            float gv = bf2f(gt[(m * 256 + i) * 256 + o]);
            tmp[(m * 256 + i) * 256 + o] = f2bf(oacc[ct][r] * gv);
        }
}

// ---------------------------------------------------------------- final projection
// tmp [32768][256] @ WfT + bfinal -> out FP32.  grid (256, 2).
__global__ __launch_bounds__(256) void k_final(const u16* __restrict__ T, const u16* __restrict__ WfT,
                                               const float* __restrict__ bfinal, float* __restrict__ out) {
    __shared__ u16 As[128 * 64];
    __shared__ u16 Bs[128 * 64];
    int lane = threadIdx.x & 63, wave = threadIdx.x >> 6;
    int rowbase = blockIdx.x * 128;
    int colbase = blockIdx.y * 128;
    f32x4 acc[4][4];
    #pragma unroll
    for (int i = 0; i < 4; i++)
        #pragma unroll
        for (int j = 0; j < 4; j++)
            acc[i][j] = (f32x4){0.f, 0.f, 0.f, 0.f};
    gemm128_core(T, WfT, rowbase, colbase, 256, As, Bs, acc, lane, wave);
    int lrow = lane & 15, quad = lane >> 4;
    int wrb = rowbase + (wave >> 1) * 64, wcb = colbase + (wave & 1) * 64;
    #pragma unroll
    for (int it = 0; it < 4; it++)
        #pragma unroll
        for (int jt = 0; jt < 4; jt++)
            #pragma unroll
            for (int r = 0; r < 4; r++) {
                int grow = wrb + it * 16 + quad * 4 + r;
                int gcol = wcb + jt * 16 + lrow;
                out[grow * 256 + gcol] = acc[it][jt][r] + bfinal[gcol];
            }
}

// ---------------------------------------------------------------- launch
extern "C" void kernel_launch(void* const* d_in, const int* in_sizes, int n_in,
                              void* d_out, int out_size, void* d_ws, size_t ws_size,
                              hipStream_t stream) {
    const float* x1d   = (const float*)d_in[0];
    const float* x2d   = (const float*)d_in[1];
    const float* ln1_g = (const float*)d_in[2];
    const float* ln1_b = (const float*)d_in[3];
    const float* ln2_g = (const float*)d_in[4];
    const float* ln2_b = (const float*)d_in[5];
    const float* Wq    = (const float*)d_in[6];
    const float* Wk    = (const float*)d_in[7];
    const float* Wv    = (const float*)d_in[8];
    const float* W2d   = (const float*)d_in[9];
    const float* Wg    = (const float*)d_in[10];
    const float* bg    = (const float*)d_in[11];
    const float* Wf    = (const float*)d_in[12];
    const float* bfin  = (const float*)d_in[13];
    float* out = (float*)d_out;

    char* ws = (char*)d_ws;
    u16*   x1   = (u16*)(ws);                    // 16,777,216 B  (reused as tmp)
    u16*   WT   = (u16*)(ws + 16777216);         //    524,288 B
    u16*   WfT  = (u16*)(ws + 17301504);         //    131,072 B
    float* bias = (float*)(ws + 17432576);       //  2,097,152 B
    u16*   qb   = (u16*)(ws + 19529728);         // 16,777,216 B
    u16*   kb   = (u16*)(ws + 36306944);         // 16,777,216 B
    u16*   vtb  = (u16*)(ws + 53084160);         // 16,777,216 B
    u16*   gb   = (u16*)(ws + 69861376);         // 16,777,216 B  (end: 86,638,592)
    u16*   tmp  = x1;                            // x1 dead after k_qkvg

    k_transpose<<<1280, 256, 0, stream>>>(Wq, Wk, Wv, Wg, Wf, WT, WfT);
    k_ln1<<<8192, 256, 0, stream>>>(x1d, ln1_g, ln1_b, x1);
    k_ln2bias<<<16384, 256, 0, stream>>>(x2d, ln2_g, ln2_b, W2d, bias);
    k_qkvg<<<dim3(256, 8), 256, 0, stream>>>(x1, WT, qb, kb, vtb, gb, bg);
    k_attn<<<dim3(128, 8, 4), 256, 0, stream>>>(qb, kb, vtb, gb, bias, tmp);
    k_final<<<dim3(256, 2), 256, 0, stream>>>(tmp, WfT, bfin, out);
}